// Round 4
// baseline (614.428 us; speedup 1.0000x reference)
//
#include <hip/hip_runtime.h>

// Problem constants (fixed by the reference's setup_inputs)
#define QS_ 512
#define B_  8
#define C_  1024
#define H_  16
#define HC_ 64
#define M_  1536
#define KS_ 512

typedef __attribute__((ext_vector_type(8))) short bf16x8;
typedef __attribute__((ext_vector_type(4))) float f32x4;

__device__ __forceinline__ short f2bf(float f) {
    unsigned u = __float_as_uint(f);
    unsigned r = (u + 0x7FFF + ((u >> 16) & 1)) >> 16;   // RNE
    return (short)r;
}

__device__ __forceinline__ void gload_lds16(const void* g, void* l) {
    __builtin_amdgcn_global_load_lds(
        (const __attribute__((address_space(1))) unsigned int*)g,
        (__attribute__((address_space(3))) unsigned int*)l, 16, 0, 0);
}

// ---------------------------------------------------------------------------
// f32 -> bf16 elementwise convert. 8 elems/thread. n % 8 == 0.
// ---------------------------------------------------------------------------
__global__ __launch_bounds__(256) void cvt_f32_bf16(
    const float* __restrict__ src, short* __restrict__ dst, int n8)
{
    int i = blockIdx.x * 256 + threadIdx.x;
    if (i >= n8) return;
    const float4* s = (const float4*)src + (size_t)i * 2;
    float4 a = s[0], bq = s[1];
    short o[8];
    o[0] = f2bf(a.x);  o[1] = f2bf(a.y);  o[2] = f2bf(a.z);  o[3] = f2bf(a.w);
    o[4] = f2bf(bq.x); o[5] = f2bf(bq.y); o[6] = f2bf(bq.z); o[7] = f2bf(bq.w);
    *(uint4*)(dst + (size_t)i * 8) = *(uint4*)o;
}

// ---------------------------------------------------------------------------
// memory_kv [t][b][h][128] f32  ->  bf16 [b][h][t][128].
// One thread = 32 contiguous f32 of one (t,b,h) row.
// ---------------------------------------------------------------------------
__global__ __launch_bounds__(256) void mkv_reshape_bf16(
    const float* __restrict__ mkv, short* __restrict__ dst)
{
    int gid = blockIdx.x * 256 + threadIdx.x;   // 0 .. M*B*H*4-1
    int part = gid & 3;
    int row  = gid >> 2;                        // t*B*H + b*H + h
    int h = row & (H_ - 1);
    int tb = row >> 4;
    int b = tb & (B_ - 1);
    int t = tb >> 3;
    const float4* s = (const float4*)(mkv + (size_t)row * 128 + part * 32);
    short o[32];
#pragma unroll
    for (int j = 0; j < 8; ++j) {
        float4 f = s[j];
        o[j * 4 + 0] = f2bf(f.x); o[j * 4 + 1] = f2bf(f.y);
        o[j * 4 + 2] = f2bf(f.z); o[j * 4 + 3] = f2bf(f.w);
    }
    short* d = dst + (((size_t)(b * H_ + h) * M_ + t) * 128 + part * 32);
#pragma unroll
    for (int j = 0; j < 4; ++j)
        ((uint4*)d)[j] = ((uint4*)o)[j];
}

// ---------------------------------------------------------------------------
// m97-style bf16 NT GEMM: out[n][j] = sum_k A[n][k]*W[j][k] + bias[j]
// A: [4096][1024] bf16, W: [1024][1024] bf16. Tile 128(M)x64(N), BK=64,
// global_load_lds width=16 staging (unpadded LDS — required by the DMA),
// 4 waves: 2x2 split, each wave 64x32 = 4x2 16x16x32 tiles.
// Grid (32,16) = 512 blocks = 2/CU.
// ---------------------------------------------------------------------------
template <bool BF16OUT>
__global__ __launch_bounds__(256) void gemm_bt_bf16(
    const short* __restrict__ A, const short* __restrict__ W,
    const float* __restrict__ bias, void* __restrict__ outv)
{
    __shared__ short As[128][64];
    __shared__ short Ws[64][64];
    const int tid  = threadIdx.x;
    const int lane = tid & 63;
    const int wave = tid >> 6;
    const int wm = (wave & 1) * 64;
    const int wn = (wave >> 1) * 32;
    const int lr = lane & 15;
    const int quad = lane >> 4;
    const int n0 = blockIdx.x * 128;
    const int j0 = blockIdx.y * 64;

    f32x4 acc[4][2];
#pragma unroll
    for (int i = 0; i < 4; ++i)
#pragma unroll
        for (int j = 0; j < 2; ++j)
            acc[i][j] = (f32x4){0.f, 0.f, 0.f, 0.f};

    for (int k0 = 0; k0 < C_; k0 += 64) {
        // A tile: 128 rows x 64 k = 16 KB -> 4 DMA issues of 256 x 16 B
#pragma unroll
        for (int p = 0; p < 4; ++p) {
            int flat = p * 256 + tid;
            int r = flat >> 3, c8 = (flat & 7) * 8;
            gload_lds16(A + (size_t)(n0 + r) * C_ + k0 + c8, (short*)As + flat * 8);
        }
        // W tile: 64 x 64 = 8 KB -> 2 issues
#pragma unroll
        for (int p = 0; p < 2; ++p) {
            int flat = p * 256 + tid;
            int r = flat >> 3, c8 = (flat & 7) * 8;
            gload_lds16(W + (size_t)(j0 + r) * C_ + k0 + c8, (short*)Ws + flat * 8);
        }
        __syncthreads();
#pragma unroll
        for (int ks = 0; ks < 2; ++ks) {
            const int kk = ks * 32 + quad * 8;
            bf16x8 afrag[4], bfrag[2];
#pragma unroll
            for (int im = 0; im < 4; ++im)
                afrag[im] = *(const bf16x8*)&As[wm + im * 16 + lr][kk];
#pragma unroll
            for (int jn = 0; jn < 2; ++jn)
                bfrag[jn] = *(const bf16x8*)&Ws[wn + jn * 16 + lr][kk];
#pragma unroll
            for (int im = 0; im < 4; ++im)
#pragma unroll
                for (int jn = 0; jn < 2; ++jn)
                    acc[im][jn] = __builtin_amdgcn_mfma_f32_16x16x32_bf16(
                        afrag[im], bfrag[jn], acc[im][jn], 0, 0, 0);
        }
        __syncthreads();
    }

#pragma unroll
    for (int jn = 0; jn < 2; ++jn) {
        const int col = j0 + wn + jn * 16 + lr;
        const float bv = bias[col];
#pragma unroll
        for (int im = 0; im < 4; ++im) {
            const int row = n0 + wm + im * 16 + quad * 4;
#pragma unroll
            for (int r = 0; r < 4; ++r) {
                float v = acc[im][jn][r] + bv;
                if (BF16OUT)
                    ((short*)outv)[(size_t)(row + r) * C_ + col] = f2bf(v);
                else
                    ((float*)outv)[(size_t)(row + r) * C_ + col] = v;
            }
        }
    }
}

// ---------------------------------------------------------------------------
// MFMA flash attention v2. Block = 64 q rows x (h,b); b fastest in grid for
// load balance. All K/V sources pre-converted bf16; register prefetch of the
// next chunk overlaps staging-load latency with QK/softmax/PV compute.
// ---------------------------------------------------------------------------
__global__ __launch_bounds__(256) void mem_attn_mfma2(
    const short* __restrict__ qb, const short* __restrict__ kb,
    const short* __restrict__ vb, const short* __restrict__ mkvb,
    const int* __restrict__ mlen, const int* __restrict__ padv,
    const unsigned char* __restrict__ maskb, short* __restrict__ xout)
{
    __shared__ short Ks[64][72];   // [t_local][hc]   pad 72: frag reads 2-way
    __shared__ short Vt[64][72];   // [hc][t_local]
    __shared__ short Pl[64][72];   // [q_local][t_local]
    const int tid  = threadIdx.x;
    const int lane = tid & 63;
    const int wave = tid >> 6;
    const int lr   = lane & 15;
    const int quad = lane >> 4;
    const int bx = blockIdx.x;
    const int b  = bx & 7;             // fastest: balances variable tend
    const int h  = (bx >> 3) & 15;
    const int s0 = (bx >> 7) * 64;
    const int L  = mlen[b];
    const int P  = padv[b];
    const int tend = L + P;
    const float NEG = -1e30f;

    // Q fragments straight from global (once)
    const short* qrow = qb + ((size_t)(s0 + wave * 16 + lr) * B_ + b) * C_ + h * HC_;
    bf16x8 aq0 = *(const bf16x8*)(qrow + quad * 8);
    bf16x8 aq1 = *(const bf16x8*)(qrow + 32 + quad * 8);

    f32x4 Oacc[4];
#pragma unroll
    for (int i = 0; i < 4; ++i) Oacc[i] = (f32x4){0.f, 0.f, 0.f, 0.f};
    float mrow[4] = {NEG, NEG, NEG, NEG};
    float lrow[4] = {0.f, 0.f, 0.f, 0.f};

    const int tl = tid >> 2;      // staging row 0..63
    const int cg = tid & 3;       // col group
    const int c0 = cg * 16;
    const short* mkvbase = mkvb + (size_t)(b * H_ + h) * M_ * 128;

    auto load_kv = [&](int t0c, short* tk, short* tv) {
        const int t = t0c + tl;
        if (t < L) {
            const short* src = mkvbase + (size_t)t * 128;
            *(uint4*)&tk[0] = *(const uint4*)(src + c0);
            *(uint4*)&tk[8] = *(const uint4*)(src + c0 + 8);
            *(uint4*)&tv[0] = *(const uint4*)(src + 64 + c0);
            *(uint4*)&tv[8] = *(const uint4*)(src + 64 + c0 + 8);
        } else if (t - L < P) {
            const short* ksrc = kb + ((size_t)(t - L) * B_ + b) * C_ + h * HC_ + c0;
            const short* vsrc = vb + ((size_t)(t - L) * B_ + b) * C_ + h * HC_ + c0;
            *(uint4*)&tk[0] = *(const uint4*)ksrc;
            *(uint4*)&tk[8] = *(const uint4*)(ksrc + 8);
            *(uint4*)&tv[0] = *(const uint4*)vsrc;
            *(uint4*)&tv[8] = *(const uint4*)(vsrc + 8);
        } else {
#pragma unroll
            for (int j = 0; j < 16; ++j) { tk[j] = 0; tv[j] = 0; }
        }
    };

    short tk[16], tv[16], tk2[16], tv2[16];
    const int nch = (tend + 63) >> 6;
    if (nch > 0) load_kv(0, tk, tv);

    for (int ci = 0; ci < nch; ++ci) {
        const int t0 = ci << 6;
        // ---- stage current chunk from registers ----
        *(uint4*)&Ks[tl][c0]     = *(uint4*)&tk[0];
        *(uint4*)&Ks[tl][c0 + 8] = *(uint4*)&tk[8];
#pragma unroll
        for (int jj = 0; jj < 16; ++jj) {
            int j = (jj + cg) & 15;
            Vt[c0 + j][tl] = tv[j];
        }
        // ---- prefetch next chunk (vmcnt waited only at the reg-copy below) ----
        if (ci + 1 < nch) load_kv((ci + 1) << 6, tk2, tv2);
        __syncthreads();

        // ---- S = Q . K^T ----
        f32x4 S[4];
#pragma unroll
        for (int tt = 0; tt < 4; ++tt) {
            bf16x8 bk0 = *(const bf16x8*)&Ks[tt * 16 + lr][quad * 8];
            bf16x8 bk1 = *(const bf16x8*)&Ks[tt * 16 + lr][32 + quad * 8];
            f32x4 z = (f32x4){0.f, 0.f, 0.f, 0.f};
            z = __builtin_amdgcn_mfma_f32_16x16x32_bf16(aq0, bk0, z, 0, 0, 0);
            S[tt] = __builtin_amdgcn_mfma_f32_16x16x32_bf16(aq1, bk1, z, 0, 0, 0);
        }

        // ---- mask + online softmax (C layout: row=quad*4+r, col=lr) ----
        float Sv[4][4];
        float rowmax[4] = {NEG, NEG, NEG, NEG};
#pragma unroll
        for (int tt = 0; tt < 4; ++tt) {
            const int tcol = t0 + tt * 16 + lr;
            const bool in_mem = tcol < L;
            const int off = tcol - L;
            const bool in_new = !in_mem && (off < P);
#pragma unroll
            for (int r = 0; r < 4; ++r) {
                float val = S[tt][r] * 0.125f;
                bool masked;
                if (in_mem) masked = false;
                else if (in_new) {
                    const int s = s0 + wave * 16 + quad * 4 + r;
                    masked = maskb[((size_t)s * KS_ + off) * B_ + b] != 0;
                } else masked = true;
                val = masked ? NEG : val;
                Sv[tt][r] = val;
                rowmax[r] = fmaxf(rowmax[r], val);
            }
        }
#pragma unroll
        for (int r = 0; r < 4; ++r) {
            float rm = rowmax[r];
            rm = fmaxf(rm, __shfl_xor(rm, 1, 16));
            rm = fmaxf(rm, __shfl_xor(rm, 2, 16));
            rm = fmaxf(rm, __shfl_xor(rm, 4, 16));
            rm = fmaxf(rm, __shfl_xor(rm, 8, 16));
            rowmax[r] = rm;
        }
        float pv[4][4];
#pragma unroll
        for (int r = 0; r < 4; ++r) {
            float nm = fmaxf(mrow[r], rowmax[r]);
            float al = __expf(mrow[r] - nm);
            float rs = 0.f;
#pragma unroll
            for (int tt = 0; tt < 4; ++tt) {
                float p = (Sv[tt][r] == NEG) ? 0.f : __expf(Sv[tt][r] - nm);
                pv[tt][r] = p;
                rs += p;
            }
            rs += __shfl_xor(rs, 1, 16);
            rs += __shfl_xor(rs, 2, 16);
            rs += __shfl_xor(rs, 4, 16);
            rs += __shfl_xor(rs, 8, 16);
            lrow[r] = lrow[r] * al + rs;
            mrow[r] = nm;
#pragma unroll
            for (int ht = 0; ht < 4; ++ht) Oacc[ht][r] *= al;
        }
        // ---- P (bf16) -> LDS A-layout, quad-rotated ----
#pragma unroll
        for (int jj = 0; jj < 4; ++jj) {
            int tt = (jj + quad) & 3;
#pragma unroll
            for (int r = 0; r < 4; ++r)
                Pl[wave * 16 + quad * 4 + r][tt * 16 + lr] = f2bf(pv[tt][r]);
        }
        __syncthreads();

        // ---- O += P . V ----
        bf16x8 ap0 = *(const bf16x8*)&Pl[wave * 16 + lr][quad * 8];
        bf16x8 ap1 = *(const bf16x8*)&Pl[wave * 16 + lr][32 + quad * 8];
#pragma unroll
        for (int ht = 0; ht < 4; ++ht) {
            bf16x8 bv0 = *(const bf16x8*)&Vt[ht * 16 + lr][quad * 8];
            bf16x8 bv1 = *(const bf16x8*)&Vt[ht * 16 + lr][32 + quad * 8];
            Oacc[ht] = __builtin_amdgcn_mfma_f32_16x16x32_bf16(ap0, bv0, Oacc[ht], 0, 0, 0);
            Oacc[ht] = __builtin_amdgcn_mfma_f32_16x16x32_bf16(ap1, bv1, Oacc[ht], 0, 0, 0);
        }
        __syncthreads();   // LDS free before next staging write

        // ---- rotate prefetch regs ----
#pragma unroll
        for (int j = 0; j < 16; ++j) { tk[j] = tk2[j]; tv[j] = tv2[j]; }
    }

    // ---- epilogue (bf16 out; l==0 -> zeros, matches nan_to_num) ----
#pragma unroll
    for (int r = 0; r < 4; ++r) {
        float inv = (lrow[r] > 0.f) ? 1.0f / lrow[r] : 0.f;
        const int s = s0 + wave * 16 + quad * 4 + r;
#pragma unroll
        for (int ht = 0; ht < 4; ++ht)
            xout[((size_t)s * B_ + b) * C_ + h * HC_ + ht * 16 + lr] =
                f2bf(Oacc[ht][r] * inv);
    }
}

// ---------------------------------------------------------------------------
extern "C" void kernel_launch(void* const* d_in, const int* in_sizes, int n_in,
                              void* d_out, int out_size, void* d_ws, size_t ws_size,
                              hipStream_t stream)
{
    const float* xq   = (const float*)d_in[0];
    const int*   pad  = (const int*)d_in[1];
    const unsigned char* maskb = (const unsigned char*)d_in[2];
    const int*   mlen = (const int*)d_in[3];
    const float* mkv  = (const float*)d_in[4];
    const float* Wq   = (const float*)d_in[5];
    const float* bq   = (const float*)d_in[6];
    const float* Wk   = (const float*)d_in[7];
    const float* bk   = (const float*)d_in[8];
    const float* Wv   = (const float*)d_in[9];
    const float* bv   = (const float*)d_in[10];
    const float* Wo   = (const float*)d_in[11];
    const float* bo   = (const float*)d_in[12];
    float* out = (float*)d_out;

    // Workspace layout (shorts), total ~96 MiB
    short* xqb  = (short*)d_ws;
    short* wqb  = xqb  + (size_t)4194304;
    short* wkb  = wqb  + (size_t)1048576;
    short* wvb  = wkb  + (size_t)1048576;
    short* wob  = wvb  + (size_t)1048576;
    short* mkvb = wob  + (size_t)1048576;     // 25,165,824 elems
    short* qbuf = mkvb + (size_t)25165824;
    short* kbuf = qbuf + (size_t)4194304;
    short* vbuf = kbuf + (size_t)4194304;
    short* xbuf = vbuf + (size_t)4194304;

    dim3 gblk(256);
    // 1) bf16 pre-conversions
    cvt_f32_bf16<<<dim3(2048), gblk, 0, stream>>>(xq, xqb, 524288);
    cvt_f32_bf16<<<dim3(512),  gblk, 0, stream>>>(Wq, wqb, 131072);
    cvt_f32_bf16<<<dim3(512),  gblk, 0, stream>>>(Wk, wkb, 131072);
    cvt_f32_bf16<<<dim3(512),  gblk, 0, stream>>>(Wv, wvb, 131072);
    cvt_f32_bf16<<<dim3(512),  gblk, 0, stream>>>(Wo, wob, 131072);
    mkv_reshape_bf16<<<dim3(3072), gblk, 0, stream>>>(mkv, mkvb);

    // 2) q/k/v projections (bf16 out)
    dim3 ggemm(32, 16);   // 4096/128 x 1024/64
    gemm_bt_bf16<true><<<ggemm, gblk, 0, stream>>>(xqb, wqb, bq, qbuf);
    gemm_bt_bf16<true><<<ggemm, gblk, 0, stream>>>(xqb, wkb, bk, kbuf);
    gemm_bt_bf16<true><<<ggemm, gblk, 0, stream>>>(xqb, wvb, bv, vbuf);

    // 3) attention (b fastest in flat grid for load balance)
    mem_attn_mfma2<<<dim3(1024), gblk, 0, stream>>>(qbuf, kbuf, vbuf, mkvb,
                                                    mlen, pad, maskb, xbuf);

    // 4) output projection (f32 out)
    gemm_bt_bf16<false><<<ggemm, gblk, 0, stream>>>(xbuf, wob, bo, out);
}